// Round 9
// baseline (50.389 us; speedup 1.0000x reference)
//
#include <hip/hip_runtime.h>

// Loss = (1/B) * sum_{b,i} min_j ||s[b,i]-t[b,j]||^2  (Cl(3) scalar: v*v|_0 = ||v||^2).
// d2 = ||s||^2 + 2h, h = 0.5||t||^2 - s.t. h is computed on the matrix pipe with ONE
// mfma_f32_32x32x16_bf16 per 32x32 tile using split-bf16 and the full K=16:
//   A row j (target), k0..7  = (x,y,z,n)_hi | (x,y,z,n)_lo     (n = 0.5||t||^2)
//   A row j (target), k8..15 = the same short8 (k12..15 hit zeros in B)
//   B col i (source), k0..7  = (-s_hi, 1) | (-s_hi, 1)
//   B col i (source), k8..15 = (-s_lo, 0) | 0
// Result = n - t.s + (t_lo.s_lo) ~ h with ~1e-5 abs error. Each block handles 128
// sources x ALL targets -> per-point min is final -> block sums to ONE partial.
#define BATCH 4
#define NPTS 8192
#define NTOT (BATCH * NPTS)   // 32768

typedef __attribute__((ext_vector_type(8)))  short  short8;
typedef __attribute__((ext_vector_type(16))) float  f32x16;

constexpr int GRP  = 512;          // targets staged per LDS group (8 KB)
constexpr int NGRP = NPTS / GRP;   // 16

__device__ __forceinline__ unsigned short f2bf(float f) {   // RNE f32->bf16
    unsigned u = __float_as_uint(f);
    unsigned r = u + 0x7FFFu + ((u >> 16) & 1u);
    return (unsigned short)(r >> 16);
}
__device__ __forceinline__ float bf2f(unsigned short s) {
    return __uint_as_float(((unsigned)s) << 16);
}

// grid = 256 blocks (4 batches x 64 source-chunks of 128), 256 threads.
__global__ __launch_bounds__(256) void knn_mfma_kernel(
        const float* __restrict__ src,   // (B, P, 3)
        const float* __restrict__ tgt,   // (B, P, 3)
        float* __restrict__ partials)    // 256 floats: per-block sum of min-d2
{
    __shared__ short8 tlds[GRP];         // 8 KB
    __shared__ float  wsum[4];

    int blk   = blockIdx.x;
    int b     = blk >> 6;
    int chunk = blk & 63;
    int tid   = threadIdx.x;
    int lane  = tid & 63;
    int wave  = tid >> 6;
    int col   = lane & 31;
    int khalf = lane >> 5;

    // ---- source fragment (every lane loads its column's source point) ----
    int p_local = chunk * 128 + wave * 32 + col;
    const float* sp = src + ((size_t)b * NPTS + p_local) * 3;
    float sx = sp[0], sy = sp[1], sz = sp[2];
    float ns2 = sx * sx + sy * sy + sz * sz;

    float nx = -sx, ny = -sy, nz = -sz;
    unsigned short shx = f2bf(nx), shy = f2bf(ny), shz = f2bf(nz);
    unsigned short slx = f2bf(nx - bf2f(shx)), sly = f2bf(ny - bf2f(shy)),
                   slz = f2bf(nz - bf2f(shz));
    const short ONE = (short)0x3F80;     // bf16(1.0)
    short8 Bf;
    if (khalf == 0)
        Bf = short8{ (short)shx,(short)shy,(short)shz, ONE,
                     (short)shx,(short)shy,(short)shz, ONE };
    else
        Bf = short8{ (short)slx,(short)sly,(short)slz, 0, 0,0,0,0 };

    // ---- target staging: thread converts 2 targets/group; prefetch next group ----
    const float2* tbase = (const float2*)(tgt + (size_t)b * NPTS * 3);
    float2 pa = tbase[tid * 3 + 0], pb = tbase[tid * 3 + 1], pc = tbase[tid * 3 + 2];

    float mb[8];
    #pragma unroll
    for (int i = 0; i < 8; ++i) mb[i] = INFINITY;

    for (int g = 0; g < NGRP; ++g) {
        // convert the prefetched 2 targets -> LDS
        {
            float x0 = pa.x, y0 = pa.y, z0 = pb.x;
            float x1 = pb.y, y1 = pc.x, z1 = pc.y;
            float n0 = 0.5f * (x0*x0 + y0*y0 + z0*z0);
            float n1 = 0.5f * (x1*x1 + y1*y1 + z1*z1);
            unsigned short hx = f2bf(x0), hy = f2bf(y0), hz = f2bf(z0), hn = f2bf(n0);
            tlds[2*tid] = short8{ (short)hx,(short)hy,(short)hz,(short)hn,
                                  (short)f2bf(x0 - bf2f(hx)), (short)f2bf(y0 - bf2f(hy)),
                                  (short)f2bf(z0 - bf2f(hz)), (short)f2bf(n0 - bf2f(hn)) };
            hx = f2bf(x1); hy = f2bf(y1); hz = f2bf(z1); hn = f2bf(n1);
            tlds[2*tid+1] = short8{ (short)hx,(short)hy,(short)hz,(short)hn,
                                    (short)f2bf(x1 - bf2f(hx)), (short)f2bf(y1 - bf2f(hy)),
                                    (short)f2bf(z1 - bf2f(hz)), (short)f2bf(n1 - bf2f(hn)) };
        }
        // prefetch next group's globals (latency hides under the MFMA loop)
        if (g + 1 < NGRP) {
            const float2* nb = tbase + (size_t)(g + 1) * (GRP * 3 / 2);
            pa = nb[tid * 3 + 0]; pb = nb[tid * 3 + 1]; pc = nb[tid * 3 + 2];
        }
        __syncthreads();

        #pragma unroll 4
        for (int tt = 0; tt < GRP / 32; ++tt) {
            short8 A = tlds[tt * 32 + col];      // stride-16B b128: conflict-free
            f32x16 c = {0,0,0,0,0,0,0,0,0,0,0,0,0,0,0,0};
            c = __builtin_amdgcn_mfma_f32_32x32x16_bf16(A, Bf, c, 0, 0, 0);
            #pragma unroll
            for (int i = 0; i < 8; ++i)
                mb[i] = fminf(mb[i], fminf(c[2*i], c[2*i+1]));   // -> v_min3_f32
        }
        __syncthreads();   // LDS consumed; next iter may overwrite
    }

    // ---- finalize: min over regs, across lane^32; d2; block sum ----
    float v = fminf(fminf(fminf(mb[0], mb[1]), fminf(mb[2], mb[3])),
                    fminf(fminf(mb[4], mb[5]), fminf(mb[6], mb[7])));
    v = fminf(v, __shfl_xor(v, 32, 64));         // rows 0..31 complete
    float d2 = fmaf(2.0f, v, ns2);

    // wave sum over its 32 distinct cols (both 32-lane halves hold identical d2)
    float a = d2;
    #pragma unroll
    for (int off = 16; off > 0; off >>= 1)
        a += __shfl_xor(a, off, 32);
    if (lane == 0) wsum[wave] = a;
    __syncthreads();
    if (tid == 0) partials[blk] = (wsum[0] + wsum[1]) + (wsum[2] + wsum[3]);
}

// One block: sum the 256 partials in a fixed tree; loss = total / BATCH.
__global__ __launch_bounds__(256) void reduce_kernel(
        const float* __restrict__ partials, float* __restrict__ out)
{
    __shared__ float acc[256];
    acc[threadIdx.x] = partials[threadIdx.x];
    __syncthreads();
    for (int off = 128; off > 0; off >>= 1) {
        if (threadIdx.x < off) acc[threadIdx.x] += acc[threadIdx.x + off];
        __syncthreads();
    }
    if (threadIdx.x == 0) out[0] = acc[0] * 0.25f;
}

extern "C" void kernel_launch(void* const* d_in, const int* in_sizes, int n_in,
                              void* d_out, int out_size, void* d_ws, size_t ws_size,
                              hipStream_t stream) {
    const float* src = (const float*)d_in[0];   // source_cloud (4, 8192, 3) f32
    const float* tgt = (const float*)d_in[1];   // target_cloud (4, 8192, 3) f32
    // d_in[2] = cayley (8,8,8) — Euclidean; scalar part of v*v == ||v||^2
    float* out      = (float*)d_out;
    float* partials = (float*)d_ws;             // 256 floats

    knn_mfma_kernel<<<256, 256, 0, stream>>>(src, tgt, partials);
    reduce_kernel<<<1, 256, 0, stream>>>(partials, out);
}

// Round 10
// 35.149 us; speedup vs baseline: 1.4336x; 1.4336x over previous
//
#include <hip/hip_runtime.h>

// Loss = (1/B) * sum_{b,i} min_j ||s[b,i]-t[b,j]||^2  (Cl(3) scalar: v*v|_0 = ||v||^2).
// d2 = ||s||^2 + 2h, h = 0.5||t||^2 - s.t, computed on the matrix pipe with ONE
// mfma_f32_32x32x16_bf16 per 32x32 tile (split-bf16, same scheme as R9 which
// validated absmax 0.0):
//   A row j (target): k0..7 = (x,y,z,n)_hi | (x,y,z,n)_lo ; k8..15 = same 16B
//   B col i (source): k0..7 = (-s_hi,1)|(-s_hi,1) ; k8..15 = (-s_lo,0)|0
// => n - t.s - t_lo.s_lo  (~1e-5 error).
// R10: no LDS (A read straight from a packed global array, per-lane coalesced),
// 1-wave blocks, 4 waves/SIMD, per-quarter d2 slabs + 2-stage reduce.
#define BATCH 4
#define NPTS 8192
#define NTOT (BATCH * NPTS)   // 32768

typedef __attribute__((ext_vector_type(8)))  short  short8;
typedef __attribute__((ext_vector_type(16))) float  f32x16;

constexpr int NQ    = 4;            // target quarters
constexpr int QT    = NPTS / NQ;    // 2048 targets per quarter
constexpr int TILES = QT / 32;      // 64 MFMA tiles per wave

__device__ __forceinline__ unsigned short f2bf(float f) {   // RNE f32->bf16
    unsigned u = __float_as_uint(f);
    unsigned r = u + 0x7FFFu + ((u >> 16) & 1u);
    return (unsigned short)(r >> 16);
}
__device__ __forceinline__ float bf2f(unsigned short s) {
    return __uint_as_float(((unsigned)s) << 16);
}

// Pack target j as 8 bf16: (x,y,z,n)_hi | (x,y,z,n)_lo, n = 0.5||t||^2.
__global__ __launch_bounds__(256) void prep_kernel(
        const float* __restrict__ tgt, short8* __restrict__ tq)
{
    int j = blockIdx.x * 256 + threadIdx.x;
    float x = tgt[3*j+0], y = tgt[3*j+1], z = tgt[3*j+2];
    float n = 0.5f * (x*x + y*y + z*z);
    unsigned short hx = f2bf(x), hy = f2bf(y), hz = f2bf(z), hn = f2bf(n);
    tq[j] = short8{ (short)hx, (short)hy, (short)hz, (short)hn,
                    (short)f2bf(x - bf2f(hx)), (short)f2bf(y - bf2f(hy)),
                    (short)f2bf(z - bf2f(hz)), (short)f2bf(n - bf2f(hn)) };
}

// One wave per block. wave = (b, src-chunk of 32, target quarter).
// grid = 4 * 256 * 4 = 4096 blocks -> 16 waves/CU -> 4 waves/SIMD.
__global__ __launch_bounds__(64) void knn_mfma_kernel(
        const float* __restrict__ src,     // (B, P, 3)
        const short8* __restrict__ tq,     // (B*P) packed targets
        float* __restrict__ slab)          // (NQ, NTOT) per-quarter min d2
{
    int w     = blockIdx.x;
    int q     = w & (NQ - 1);
    int chunk = (w >> 2) & 255;
    int b     = w >> 10;
    int lane  = threadIdx.x;
    int col   = lane & 31;
    int khalf = lane >> 5;

    // ---- source fragment (B): col i = my source; lane halves carry hi/lo k's ----
    int p_local = chunk * 32 + col;
    const float* sp = src + ((size_t)b * NPTS + p_local) * 3;
    float sx = sp[0], sy = sp[1], sz = sp[2];
    float ns2 = sx*sx + sy*sy + sz*sz;

    float nx = -sx, ny = -sy, nz = -sz;
    unsigned short shx = f2bf(nx), shy = f2bf(ny), shz = f2bf(nz);
    unsigned short slx = f2bf(nx - bf2f(shx)), sly = f2bf(ny - bf2f(shy)),
                   slz = f2bf(nz - bf2f(shz));
    const short ONE = (short)0x3F80;     // bf16(1.0)
    short8 Bf;
    if (khalf == 0)
        Bf = short8{ (short)shx,(short)shy,(short)shz, ONE,
                     (short)shx,(short)shy,(short)shz, ONE };
    else
        Bf = short8{ (short)slx,(short)sly,(short)slz, 0, 0,0,0,0 };

    // ---- stream the quarter's targets straight from global (L1/L2-resident) ----
    const short8* tp = tq + (size_t)b * NPTS + (size_t)q * QT;

    float mb[8];
    #pragma unroll
    for (int i = 0; i < 8; ++i) mb[i] = INFINITY;

    short8 Anext = tp[col];                       // coalesced dwordx4 per lane
    #pragma unroll 4
    for (int tt = 0; tt < TILES; ++tt) {
        short8 A = Anext;
        if (tt + 1 < TILES) Anext = tp[(tt + 1) * 32 + col];
        f32x16 c = {0,0,0,0,0,0,0,0,0,0,0,0,0,0,0,0};
        c = __builtin_amdgcn_mfma_f32_32x32x16_bf16(A, Bf, c, 0, 0, 0);
        #pragma unroll
        for (int i = 0; i < 8; ++i)
            mb[i] = fminf(mb[i], fminf(c[2*i], c[2*i+1]));   // -> v_min3_f32
    }

    // ---- finalize: min over 16 regs + lane^32; d2; one coalesced store ----
    float v = fminf(fminf(fminf(mb[0], mb[1]), fminf(mb[2], mb[3])),
                    fminf(fminf(mb[4], mb[5]), fminf(mb[6], mb[7])));
    v = fminf(v, __shfl_xor(v, 32, 64));
    float d2 = fmaf(2.0f, v, ns2);
    if (lane < 32)
        slab[(size_t)q * NTOT + (size_t)b * NPTS + p_local] = d2;
}

// Stage 1: 64 blocks x 512 points: min across the 4 quarter-slabs, block tree-sum.
__global__ __launch_bounds__(256) void reduce1_kernel(
        const float* __restrict__ slab, float* __restrict__ partials)
{
    __shared__ float acc[256];
    int base = blockIdx.x * 512;
    float a = 0.0f;
    #pragma unroll
    for (int p = 0; p < 2; ++p) {
        int i = base + threadIdx.x + p * 256;
        float m = fminf(fminf(slab[i],            slab[NTOT + i]),
                        fminf(slab[2*NTOT + i],   slab[3*NTOT + i]));
        a += m;
    }
    acc[threadIdx.x] = a;
    __syncthreads();
    for (int off = 128; off > 0; off >>= 1) {
        if (threadIdx.x < off) acc[threadIdx.x] += acc[threadIdx.x + off];
        __syncthreads();
    }
    if (threadIdx.x == 0) partials[blockIdx.x] = acc[0];
}

// Stage 2: one wave sums the 64 partials; loss = total / BATCH.
__global__ __launch_bounds__(64) void reduce2_kernel(
        const float* __restrict__ partials, float* __restrict__ out)
{
    float v = partials[threadIdx.x];
    #pragma unroll
    for (int off = 32; off > 0; off >>= 1)
        v += __shfl_down(v, off, 64);
    if (threadIdx.x == 0) out[0] = v * 0.25f;
}

extern "C" void kernel_launch(void* const* d_in, const int* in_sizes, int n_in,
                              void* d_out, int out_size, void* d_ws, size_t ws_size,
                              hipStream_t stream) {
    const float* src = (const float*)d_in[0];   // source_cloud (4, 8192, 3) f32
    const float* tgt = (const float*)d_in[1];   // target_cloud (4, 8192, 3) f32
    // d_in[2] = cayley (8,8,8) — Euclidean; scalar part of v*v == ||v||^2
    float* out = (float*)d_out;

    // ws: tq packed targets (512 KiB) | slab (512 KiB) | partials (256 B)
    short8* tq       = (short8*)d_ws;
    float*  slab     = (float*)((char*)d_ws + (size_t)NTOT * sizeof(short8));
    float*  partials = slab + (size_t)NQ * NTOT;

    prep_kernel<<<NTOT / 256, 256, 0, stream>>>(tgt, tq);
    knn_mfma_kernel<<<BATCH * 256 * NQ, 64, 0, stream>>>(src, tq, slab);
    reduce1_kernel<<<64, 256, 0, stream>>>(slab, partials);
    reduce2_kernel<<<1, 64, 0, stream>>>(partials, out);
}

// Round 11
// 35.022 us; speedup vs baseline: 1.4388x; 1.0036x over previous
//
#include <hip/hip_runtime.h>

// Loss = (1/B) * sum_{b,i} min_j ||s[b,i]-t[b,j]||^2  (Cl(3) scalar: v*v|_0 = ||v||^2).
// d2 = ||s||^2 + 2h, h = 0.5||t||^2 - s.t, via ONE mfma_f32_32x32x16_bf16 per
// 32x32 tile (split-bf16; validated absmax 0.0 in R9/R10):
//   A row j (target): k0..7 = (x,y,z,n)_hi | (x,y,z,n)_lo ; k8..15 = same 16B
//   B col i (source): k0..7 = (-s_hi,1)|(-s_hi,1) ; k8..15 = (-s_lo,0)|0
// R11 vs R10: persistent zero-C (kills 16 accvgpr zero-writes per tile),
// prefetch depth 2 (wrapped indices, branchless), NQ=8 for 2x TLP.
#define BATCH 4
#define NPTS 8192
#define NTOT (BATCH * NPTS)   // 32768

typedef __attribute__((ext_vector_type(8)))  short  short8;
typedef __attribute__((ext_vector_type(16))) float  f32x16;

constexpr int NQ    = 8;            // target chunks per batch
constexpr int QT    = NPTS / NQ;    // 1024 targets per chunk
constexpr int TILES = QT / 32;      // 32 MFMA tiles per wave (power of 2)

__device__ __forceinline__ unsigned short f2bf(float f) {   // RNE f32->bf16
    unsigned u = __float_as_uint(f);
    unsigned r = u + 0x7FFFu + ((u >> 16) & 1u);
    return (unsigned short)(r >> 16);
}
__device__ __forceinline__ float bf2f(unsigned short s) {
    return __uint_as_float(((unsigned)s) << 16);
}

// Pack target j as 8 bf16: (x,y,z,n)_hi | (x,y,z,n)_lo, n = 0.5||t||^2.
__global__ __launch_bounds__(256) void prep_kernel(
        const float* __restrict__ tgt, short8* __restrict__ tq)
{
    int j = blockIdx.x * 256 + threadIdx.x;
    float x = tgt[3*j+0], y = tgt[3*j+1], z = tgt[3*j+2];
    float n = 0.5f * (x*x + y*y + z*z);
    unsigned short hx = f2bf(x), hy = f2bf(y), hz = f2bf(z), hn = f2bf(n);
    tq[j] = short8{ (short)hx, (short)hy, (short)hz, (short)hn,
                    (short)f2bf(x - bf2f(hx)), (short)f2bf(y - bf2f(hy)),
                    (short)f2bf(z - bf2f(hz)), (short)f2bf(n - bf2f(hn)) };
}

// One wave per block: (b, 32-source chunk, target 1/8th).
// grid = 4 * 256 * 8 = 8192 waves -> up to 8 waves/SIMD.
__global__ __launch_bounds__(64) void knn_mfma_kernel(
        const float* __restrict__ src,     // (B, P, 3)
        const short8* __restrict__ tq,     // (B*P) packed targets
        float* __restrict__ slab)          // (NQ, NTOT) per-chunk min d2
{
    int w     = blockIdx.x;
    int q     = w & (NQ - 1);
    int chunk = (w >> 3) & 255;
    int b     = w >> 11;
    int lane  = threadIdx.x;
    int col   = lane & 31;
    int khalf = lane >> 5;

    // ---- source fragment (B operand): col = my source point ----
    int p_local = chunk * 32 + col;
    const float* sp = src + ((size_t)b * NPTS + p_local) * 3;
    float sx = sp[0], sy = sp[1], sz = sp[2];
    float ns2 = sx*sx + sy*sy + sz*sz;

    float nx = -sx, ny = -sy, nz = -sz;
    unsigned short shx = f2bf(nx), shy = f2bf(ny), shz = f2bf(nz);
    unsigned short slx = f2bf(nx - bf2f(shx)), sly = f2bf(ny - bf2f(shy)),
                   slz = f2bf(nz - bf2f(shz));
    const short ONE = (short)0x3F80;     // bf16(1.0)
    short8 Bf;
    if (khalf == 0)
        Bf = short8{ (short)shx,(short)shy,(short)shz, ONE,
                     (short)shx,(short)shy,(short)shz, ONE };
    else
        Bf = short8{ (short)slx,(short)sly,(short)slz, 0, 0,0,0,0 };

    const short8* tp = tq + (size_t)b * NPTS + (size_t)q * QT;

    const f32x16 CZ = {0,0,0,0,0,0,0,0,0,0,0,0,0,0,0,0};   // persistent zero C

    float mb[8];
    #pragma unroll
    for (int i = 0; i < 8; ++i) mb[i] = INFINITY;

    // depth-2 prefetch, wrapped (branchless; wrapped tail loads are unused)
    short8 A0 = tp[col];
    short8 A1 = tp[32 + col];
    #pragma unroll 4
    for (int tt = 0; tt < TILES; ++tt) {
        short8 A = (tt & 1) ? A1 : A0;
        int nxt = (tt + 2) & (TILES - 1);
        if (tt & 1) A1 = tp[nxt * 32 + col]; else A0 = tp[nxt * 32 + col];
        f32x16 d = __builtin_amdgcn_mfma_f32_32x32x16_bf16(A, Bf, CZ, 0, 0, 0);
        #pragma unroll
        for (int i = 0; i < 8; ++i)
            mb[i] = fminf(mb[i], fminf(d[2*i], d[2*i+1]));   // -> v_min3_f32
    }

    // ---- finalize: min over 16 rows here + 16 rows in lane^32; d2; store ----
    float v = fminf(fminf(fminf(mb[0], mb[1]), fminf(mb[2], mb[3])),
                    fminf(fminf(mb[4], mb[5]), fminf(mb[6], mb[7])));
    v = fminf(v, __shfl_xor(v, 32, 64));
    float d2 = fmaf(2.0f, v, ns2);
    if (lane < 32)
        slab[(size_t)q * NTOT + (size_t)b * NPTS + p_local] = d2;
}

// Stage 1: 64 blocks x 512 points: min across the 8 chunk-slabs, block tree-sum.
__global__ __launch_bounds__(256) void reduce1_kernel(
        const float* __restrict__ slab, float* __restrict__ partials)
{
    __shared__ float acc[256];
    int base = blockIdx.x * 512;
    float a = 0.0f;
    #pragma unroll
    for (int p = 0; p < 2; ++p) {
        int i = base + threadIdx.x + p * 256;
        float m = INFINITY;
        #pragma unroll
        for (int sl = 0; sl < NQ; ++sl)
            m = fminf(m, slab[(size_t)sl * NTOT + i]);
        a += m;
    }
    acc[threadIdx.x] = a;
    __syncthreads();
    for (int off = 128; off > 0; off >>= 1) {
        if (threadIdx.x < off) acc[threadIdx.x] += acc[threadIdx.x + off];
        __syncthreads();
    }
    if (threadIdx.x == 0) partials[blockIdx.x] = acc[0];
}

// Stage 2: one wave sums the 64 partials; loss = total / BATCH.
__global__ __launch_bounds__(64) void reduce2_kernel(
        const float* __restrict__ partials, float* __restrict__ out)
{
    float v = partials[threadIdx.x];
    #pragma unroll
    for (int off = 32; off > 0; off >>= 1)
        v += __shfl_down(v, off, 64);
    if (threadIdx.x == 0) out[0] = v * 0.25f;
}

extern "C" void kernel_launch(void* const* d_in, const int* in_sizes, int n_in,
                              void* d_out, int out_size, void* d_ws, size_t ws_size,
                              hipStream_t stream) {
    const float* src = (const float*)d_in[0];   // source_cloud (4, 8192, 3) f32
    const float* tgt = (const float*)d_in[1];   // target_cloud (4, 8192, 3) f32
    // d_in[2] = cayley (8,8,8) — Euclidean; scalar part of v*v == ||v||^2
    float* out = (float*)d_out;

    // ws: tq packed targets (512 KiB) | slab (1 MiB) | partials (256 B)
    short8* tq       = (short8*)d_ws;
    float*  slab     = (float*)((char*)d_ws + (size_t)NTOT * sizeof(short8));
    float*  partials = slab + (size_t)NQ * NTOT;

    prep_kernel<<<NTOT / 256, 256, 0, stream>>>(tgt, tq);
    knn_mfma_kernel<<<BATCH * 256 * NQ, 64, 0, stream>>>(src, tq, slab);
    reduce1_kernel<<<64, 256, 0, stream>>>(slab, partials);
    reduce2_kernel<<<1, 64, 0, stream>>>(partials, out);
}